// Round 13
// baseline (75.756 us; speedup 1.0000x reference)
//
#include <hip/hip_runtime.h>
#include <math.h>

#define D 128
#define W 65            // D/2+1
#define NK 125
#define NB 8
#define SLAB (D*W)      // 8320 elements per slab
#define TWO_PI 6.28318530717958647692f
#define R2C 0.70710678118654752440f
#define C8C 0.92387953251128675613f
#define S8C 0.38268343236508977173f
#define ARS 146         // Ab row stride (float2) per column l
#define GS  67          // Gs row stride (float2): 65 needed outputs + pad
#define BRS 68          // BC row stride (float2), even -> 16B-aligned rows

// ---------------- helpers ----------------

__device__ __forceinline__ bool better(float va, int ia, float vb, int ib) {
    return (va > vb) || (va == vb && ia < ib);
}
__device__ __forceinline__ float2 cmul(float2 a, float2 b) {
    return make_float2(a.x*b.x - a.y*b.y, a.x*b.y + a.y*b.x);
}
__device__ __forceinline__ void cmac(float2& acc, float2 a, float2 b) {
    acc.x = fmaf(a.x, b.x, fmaf(-a.y, b.y, acc.x));
    acc.y = fmaf(a.x, b.y, fmaf( a.y, b.x, acc.y));
}
__device__ __forceinline__ float2 cadd(float2 a, float2 b){ return make_float2(a.x+b.x, a.y+b.y); }
__device__ __forceinline__ float2 csub(float2 a, float2 b){ return make_float2(a.x-b.x, a.y-b.y); }

// forward 8-pt FFT: a[r] = sum_j x[j] e^{-2pi i j r/8}
__device__ __forceinline__ void fft8_fwd(const float2* x, float2* a) {
    float2 e0 = x[0], o0 = x[1], e1 = x[2], o1 = x[3];
    float2 e2 = x[4], o2 = x[5], e3 = x[6], o3 = x[7];
    float2 t0 = cadd(e0, e2), t1 = csub(e0, e2);
    float2 t2 = cadd(e1, e3), t3 = csub(e1, e3);
    float2 E0 = cadd(t0, t2), E2 = csub(t0, t2);
    float2 E1 = make_float2(t1.x + t3.y, t1.y - t3.x);
    float2 E3 = make_float2(t1.x - t3.y, t1.y + t3.x);
    float2 u0 = cadd(o0, o2), u1 = csub(o0, o2);
    float2 u2 = cadd(o1, o3), u3 = csub(o1, o3);
    float2 O0 = cadd(u0, u2), O2 = csub(u0, u2);
    float2 O1 = make_float2(u1.x + u3.y, u1.y - u3.x);
    float2 O3 = make_float2(u1.x - u3.y, u1.y + u3.x);
    float2 w1 = make_float2(R2C*(O1.x + O1.y), R2C*(O1.y - O1.x));
    float2 w2 = make_float2(O2.y, -O2.x);
    float2 w3 = make_float2(R2C*(O3.y - O3.x), -R2C*(O3.x + O3.y));
    a[0] = cadd(E0, O0); a[4] = csub(E0, O0);
    a[1] = cadd(E1, w1); a[5] = csub(E1, w1);
    a[2] = cadd(E2, w2); a[6] = csub(E2, w2);
    a[3] = cadd(E3, w3); a[7] = csub(E3, w3);
}

// inverse 8-pt DFT: a[r] = sum_j x[j] e^{+2pi i j r/8}
__device__ __forceinline__ void ifft8_reg(const float2* x, float2* a) {
    float2 e0 = x[0], o0 = x[1], e1 = x[2], o1 = x[3];
    float2 e2 = x[4], o2 = x[5], e3 = x[6], o3 = x[7];
    float2 t0 = cadd(e0, e2), t1 = csub(e0, e2);
    float2 t2 = cadd(e1, e3), t3 = csub(e1, e3);
    float2 E0 = cadd(t0, t2), E2 = csub(t0, t2);
    float2 E1 = make_float2(t1.x - t3.y, t1.y + t3.x);
    float2 E3 = make_float2(t1.x + t3.y, t1.y - t3.x);
    float2 u0 = cadd(o0, o2), u1 = csub(o0, o2);
    float2 u2 = cadd(o1, o3), u3 = csub(o1, o3);
    float2 O0 = cadd(u0, u2), O2 = csub(u0, u2);
    float2 O1 = make_float2(u1.x - u3.y, u1.y + u3.x);
    float2 O3 = make_float2(u1.x + u3.y, u1.y - u3.x);
    float2 w1o = make_float2(R2C*(O1.x - O1.y), R2C*(O1.x + O1.y));
    float2 w2o = make_float2(-O2.y, O2.x);
    float2 w3o = make_float2(R2C*(-O3.x - O3.y), R2C*(O3.x - O3.y));
    a[0] = cadd(E0, O0); a[4] = csub(E0, O0);
    a[1] = cadd(E1, w1o); a[5] = csub(E1, w1o);
    a[2] = cadd(E2, w2o); a[6] = csub(E2, w2o);
    a[3] = cadd(E3, w3o); a[7] = csub(E3, w3o);
}

// ---------------- batched 128-pt FFT: fft16 regs + radix-8 second stage -----
// MODE 0: real rows (float in, contiguous), write k<=64 to out[l*65+k]
// MODE 1: complex, base=(l/65)*SLAB+l%65, stride 65, shift-folded, same layout
// MODE 2: complex, base=l, stride SLAB, shift-folded, same layout
// MODE 4: MODE1 + transposed write + ctf multiply (S = parts_rfft * ctf)

template<int MODE>
__device__ __forceinline__ void fft128v2(const float* __restrict__ inf,
                                         const float2* __restrict__ inc,
                                         float2* __restrict__ out,
                                         const float* __restrict__ ct,
                                         int l0, int nlines,
                                         float2* __restrict__ Fl,
                                         float2* __restrict__ twf) {
    int tid = threadIdx.x;
    int line, t;
    if (MODE == 0) { t = tid & 7; line = tid >> 3; }
    else           { line = tid & 31; t = tid >> 5; }
    int l = l0 + line;
    bool live = (l < nlines);

    if (tid < 128) {
        float s, c;
        sincosf(-TWO_PI * (float)tid / 128.0f, &s, &c);
        twf[tid] = make_float2(c, s);
    }

    int base = 0, stride = 1;
    if (MODE == 1 || MODE == 4) { base = (l / W) * SLAB + (l % W); stride = W; }
    else if (MODE == 2) { base = l; stride = SLAB; }

    float2 xe[8], xo[8];
    if (live) {
        if (MODE == 0) {
            const float* r = inf + (size_t)l * D;
            #pragma unroll
            for (int j = 0; j < 8; ++j) {
                xe[j] = make_float2(r[t + 16*j], 0.f);
                xo[j] = make_float2(r[t + 8 + 16*j], 0.f);
            }
        } else {
            #pragma unroll
            for (int j = 0; j < 8; ++j) {
                xe[j] = inc[base + (t + 16*j) * stride];
                xo[j] = inc[base + (t + 8 + 16*j) * stride];
            }
        }
    } else {
        #pragma unroll
        for (int j = 0; j < 8; ++j) { xe[j] = make_float2(0,0); xo[j] = make_float2(0,0); }
    }
    float2 E[8], O[8];
    fft8_fwd(xe, E);
    fft8_fwd(xo, O);
    {
        const float2 w16[8] = {
            { 1.f, 0.f }, { C8C, -S8C }, { R2C, -R2C }, { S8C, -C8C },
            { 0.f, -1.f }, { -S8C, -C8C }, { -R2C, -R2C }, { -C8C, -S8C }
        };
        float2* Fp = Fl + line * 137 + t * 17;
        #pragma unroll
        for (int kk = 0; kk < 8; ++kk) {
            float2 wo = cmul(w16[kk], O[kk]);
            Fp[kk]     = cadd(E[kk], wo);
            Fp[kk + 8] = csub(E[kk], wo);
        }
    }
    __syncthreads();
    if (live) {
        const float2* Fr = Fl + line * 137;
        #pragma unroll
        for (int half = 0; half < 2; ++half) {
            int kk = t + 8 * half;
            float2 Gv[8];
            #pragma unroll
            for (int tt = 0; tt < 8; ++tt) {
                Gv[tt] = cmul(Fr[tt * 17 + kk], twf[(tt * kk) & 127]);
            }
            float2 o[8];
            fft8_fwd(Gv, o);   // o[s] = out frequency k = kk + 16 s
            if (MODE == 0) {
                #pragma unroll
                for (int s = 0; s < 8; ++s) {
                    int kf = kk + 16 * s;
                    if (kf <= 64) out[(size_t)l * W + kf] = o[s];
                }
            } else {
                #pragma unroll
                for (int s = 0; s < 8; ++s) {
                    int slot = (kk + 16 * s) ^ 64;   // fftshift fold
                    if (MODE == 4) {
                        float cf = ct[(size_t)l * D + slot];
                        out[(size_t)l * D + slot] = make_float2(o[s].x * cf, o[s].y * cf);
                    } else {
                        out[base + slot * stride] = o[s];
                    }
                }
            }
        }
    }
}

// ---------------- merged prologue kernels ----------------

// K1: vol x-FFT (512 blks) | parts x-FFT (32) | rot (1) | ctf transpose (260)
__global__ __launch_bounds__(256) void k1_kernel(const float* __restrict__ vol,
                                                 const float* __restrict__ parts,
                                                 const float* __restrict__ ctf,
                                                 const float* __restrict__ euler,
                                                 float2* __restrict__ bufA,
                                                 float2* __restrict__ pT1,
                                                 float* __restrict__ CT,
                                                 float* __restrict__ rot) {
    __shared__ float2 Fl[32 * 137];
    __shared__ float2 twf[128];
    int bid = blockIdx.x;
    int tid = threadIdx.x;
    if (bid < 512) {
        fft128v2<0>(vol, nullptr, bufA, nullptr, bid * 32, D*D, Fl, twf);
    } else if (bid < 544) {
        fft128v2<0>(parts, nullptr, pT1, nullptr, (bid - 512) * 32, NB*D, Fl, twf);
    } else if (bid == 544) {
        int k = tid;
        if (k < NK) {
            const float d2r = 0.017453292519943295f;
            float a = euler[k*3+0]*d2r, b = euler[k*3+1]*d2r, c = euler[k*3+2]*d2r;
            float sa, ca, sb, cb, sc, cc;
            sincosf(a, &sa, &ca); sincosf(b, &sb, &cb); sincosf(c, &sc, &cc);
            rot[k*9+0] =  ca*cb*cc - sa*sc;
            rot[k*9+1] = -ca*cb*sc - sa*cc;
            rot[k*9+2] =  ca*sb;
            rot[k*9+3] =  sa*cb*cc + ca*sc;
            rot[k*9+4] = -sa*cb*sc + ca*cc;
            rot[k*9+5] =  sa*sb;
            rot[k*9+6] = -sb*cc;
            rot[k*9+7] =  sb*sc;
            rot[k*9+8] =  cb;
        }
    } else {
        int i = (bid - 545) * 256 + tid;
        if (i < NB * W * D) {
            int m = i & (D-1);
            int t2 = i >> 7;
            int x = t2 % W;
            int b = t2 / W;
            CT[i] = ctf[b * SLAB + m * W + x];
        }
    }
}

// K2: vol y-FFT (260 blks) | parts y-FFT transposed with ctf fold (17)
__global__ __launch_bounds__(256) void k2_kernel(const float2* __restrict__ bufA,
                                                 float2* __restrict__ bufB,
                                                 const float2* __restrict__ pT1,
                                                 float2* __restrict__ ST,
                                                 const float* __restrict__ CT) {
    __shared__ float2 Fl[32 * 137];
    __shared__ float2 twf[128];
    int bid = blockIdx.x;
    if (bid < 260) fft128v2<1>(nullptr, bufA, bufB, nullptr, bid * 32, D*W, Fl, twf);
    else           fft128v2<4>(nullptr, pT1, ST, CT, (bid - 260) * 32, NB*W, Fl, twf);
}

// K3: vol z-FFT
__global__ __launch_bounds__(256) void k3_kernel(const float2* __restrict__ bufB,
                                                 float2* __restrict__ bufA) {
    __shared__ float2 Fl[32 * 137];
    __shared__ float2 twf[128];
    fft128v2<2>(nullptr, bufB, bufA, nullptr, blockIdx.x * 32, SLAB, Fl, twf);
}

// ---------------- central-slice projection (transposed write) ----------------
// Bijective XCD-chunked block swizzle + early-out beyond the Nyquist disc.

__global__ __launch_bounds__(256) void proj_kernel(const float2* __restrict__ vol,
                                                   const float* __restrict__ rot,
                                                   float2* __restrict__ projT) {
    int bid = blockIdx.x;
    int xcd = bid & 7, ii = bid >> 3;
    int wg = (xcd < 7) ? (xcd * 508 + ii) : (3556 + ii);
    int idx = wg * 256 + threadIdx.x;
    if (idx >= NK * D * W) return;
    int h = idx & (D-1);
    int t2 = idx >> 7;
    int w = t2 % W;
    int k = t2 / W;
    int yy = h - 64;
    if (w*w + yy*yy > 4096) { projT[idx] = make_float2(0.f, 0.f); return; }
    float x = (float)w;
    float y = (float)yy;
    const float* R = rot + k*9;
    float rx = R[0]*x + R[1]*y;
    float ry = R[3]*x + R[4]*y;
    float rz = R[6]*x + R[7]*y;
    bool neg = rx < 0.0f;
    if (neg) { rx = -rx; ry = -ry; rz = -rz; }
    float xi = rx;
    float yi = ry + 64.0f;
    float zi = rz + 64.0f;
    float z0 = floorf(zi), y0 = floorf(yi), x0 = floorf(xi);
    float tz = zi - z0, ty = yi - y0, tx = xi - x0;
    int z0i = (int)z0, y0i = (int)y0, x0i = (int)x0;
    float ar = 0.f, ai = 0.f;
    for (int dz = 0; dz < 2; ++dz) {
        float wz = dz ? tz : 1.0f - tz;
        int zc = z0i + dz;
        bool vz = (zc >= 0) && (zc < D);
        int zx = min(max(zc, 0), D-1);
        for (int dy = 0; dy < 2; ++dy) {
            float wy = dy ? ty : 1.0f - ty;
            int yc = y0i + dy;
            bool vy = (yc >= 0) && (yc < D);
            int yx = min(max(yc, 0), D-1);
            for (int dx = 0; dx < 2; ++dx) {
                float wx = dx ? tx : 1.0f - tx;
                int xc = x0i + dx;
                bool vx = (xc >= 0) && (xc < W);
                int xx = min(max(xc, 0), W-1);
                float wt = (vz && vy && vx) ? wz*wy*wx : 0.0f;
                float2 v = vol[zx * SLAB + yx * W + xx];
                ar = fmaf(wt, v.x, ar);
                ai = fmaf(wt, v.y, ai);
            }
        }
    }
    if (neg) ai = -ai;
    projT[idx] = make_float2(ar, ai);
}

// ---------------- fused correlate + windowed irfft2 + top2 ----------------
// 512-thread blocks, 2 (b,k) pairs per block (half-block each, per-half LDS,
// shared tw). Pairs 2L/2L+1 share the same k -> shared Jk L2 locality.
// Grid 500 <= 512 resident slots at 2 blocks/CU -> single balanced round,
// 16 waves/CU. launch_bounds(512,4): VGPR cap 128 (twr cache re-added).
// Spill watchdog: WRITE_SIZE must stay ~26 KB.

__global__ __launch_bounds__(512, 4) void corr_kernel(const float2* __restrict__ ST,
                                                      const float2* __restrict__ PJT,
                                                      float* __restrict__ outv) {
    __shared__ float2 tw[128];                         // e^{+2 pi i n/128}
    __shared__ __align__(16) float2 AbBC2[2][17*ARS];  // per-half stage1/BC
    __shared__ float2 Gs2[2][17*GS];                   // per-half column-iFFT outs
    __shared__ float  Ny2[2][65];
    __shared__ float  redv[16];
    __shared__ int    redi[16];

    int tid = threadIdx.x;
    int half = tid >> 8;
    int t = tid & 255;
    int g = blockIdx.x;
    int xcd = g & 7, ii = g >> 3;
    int L = (xcd < 4) ? (xcd * 63 + ii) : (252 + (xcd - 4) * 62 + ii);
    int pair = 2 * L + half;
    int k = pair >> 3;
    int b = pair & 7;
    const float inv_d = 1.0f / 128.0f;

    if (tid < 128) {
        float s, c;
        sincosf(TWO_PI * (float)tid / 128.0f, &s, &c);
        tw[tid] = make_float2(c, s);
    }

    float2* AbBC = AbBC2[half];
    float2* Gs   = Gs2[half];
    float*  Ny   = Ny2[half];

    const float2* Sb = ST + b * (W * D);
    const float2* Jk = PJT + k * (W * D);

    int lane = t & 63;          // acc: v = lane
    int wv = t >> 6;            // per-half wave id; acc uu block = wv*16 + j
    int sv = lane & 7;
    int vp = (96 + lane) & 127;
    float acc[16];
    #pragma unroll
    for (int j = 0; j < 16; ++j) acc[j] = 0.0f;
    float accR = 0.0f;          // rim accumulator (t<129)
    int ur = 0, vr = 0;
    if (t < 129) { if (t < 65) { ur = 64; vr = t; } else { ur = t - 65; vr = 64; } }

    __syncthreads();

    float2 wvp = tw[vp];
    float2 tq = make_float2(1.0f, 0.0f);   // tw[x*vp], x running 0..15

    int m01 = t & 15;
    float2 twr[8];                         // pre-twiddle tw[r*m01] (valid all stage1 tasks)
    twr[0] = make_float2(1.f, 0.f);
    #pragma unroll
    for (int r = 1; r < 8; ++r) twr[r] = tw[(r * m01) & 127];

    for (int cg = 0; cg < 4; ++cg) {
        // ---- stage1: product + 8-pt iFFT over m1 + pre-twiddle -> Ab
        {
            int lim1 = (cg == 0) ? 17 * 16 : 16 * 16;
            for (int i = t; i < lim1; i += 256) {
                int l = i >> 4, m0 = i & 15;   // m0 == m01
                int x = (l < 16) ? (4*cg + (l >> 2) + 16 * (l & 3)) : 64;
                const float2* Sx = Sb + x * 128 + m0;
                const float2* Jx = Jk + x * 128 + m0;
                float2 p[8];
                #pragma unroll
                for (int j = 0; j < 8; ++j) {
                    float2 s = Sx[16*j];
                    float2 pj = Jx[16*j];
                    p[j] = make_float2(s.x*pj.x + s.y*pj.y, s.y*pj.x - s.x*pj.y);
                }
                float2 A[8];
                ifft8_reg(p, A);
                float2* dst = AbBC + l * ARS + m0;
                dst[0] = A[0];
                #pragma unroll
                for (int r = 1; r < 8; ++r) dst[r*18] = cmul(A[r], twr[r]);
            }
        }
        __syncthreads();
        // ---- stage2: 16-pt register iFFT per (l, r); store only needed k's
        {
            int lim2 = (cg == 0) ? 136 : 128;
            for (int i = t; i < lim2; i += 256) {
                int l, r;
                if (i < 128) { l = i & 15; r = i >> 4; }
                else         { l = 16; r = i - 128; }
                const float4* Ar = (const float4*)(AbBC + l * ARS + r * 18);
                float2 xe[8], xo[8];
                #pragma unroll
                for (int j = 0; j < 8; ++j) {
                    float4 a = Ar[j];
                    xe[j] = make_float2(a.x, a.y);
                    xo[j] = make_float2(a.z, a.w);
                }
                float2 E[8], O[8];
                ifft8_reg(xe, E);
                ifft8_reg(xo, O);
                const float2 w16p[8] = {
                    { 1.f, 0.f }, { C8C, S8C }, { R2C, R2C }, { S8C, C8C },
                    { 0.f, 1.f }, { -S8C, C8C }, { -R2C, R2C }, { -C8C, S8C }
                };
                float2* Gl = Gs + l * GS;
                #pragma unroll
                for (int tt = 0; tt < 8; ++tt) {
                    float2 wo = cmul(w16p[tt], O[tt]);
                    float2 lowv  = cadd(E[tt], wo);   // freq k = r + 8tt
                    float2 highv = csub(E[tt], wo);   // freq k + 64
                    int klow = r + 8*tt;
                    if (tt <= 3) Gl[klow + 32] = lowv;           // k<=31 -> u2=k+32
                    if (tt == 4 && r == 0) Gl[64] = lowv;        // k=32  -> u2=64
                    if (tt >= 4) Gl[klow - 32] = highv;          // k+64>=96 -> u2=k-32
                }
            }
        }
        __syncthreads();
        // ---- B stage: read Gs directly by u2, scale, x1 butterfly -> BC, Ny
        {
            float2* BC = AbBC;   // Ab dead; overlay
            int lim = (cg == 0) ? 325 : 260;
            for (int i = t; i < lim; i += 256) {
                if (i < 260) {
                    int q = i / 65;
                    int u2 = i - q * 65;
                    float sg = (u2 & 1) ? -inv_d : inv_d;
                    const float2* Gq = Gs + (4*q) * GS + u2;
                    float2 h0 = Gq[0*GS];
                    float2 h1 = Gq[1*GS];
                    float2 h2 = Gq[2*GS];
                    float2 h3 = Gq[3*GS];
                    h0.x *= sg; h0.y *= sg; h1.x *= sg; h1.y *= sg;
                    h2.x *= sg; h2.y *= sg; h3.x *= sg; h3.y *= sg;
                    if (cg == 0 && q == 0) { h0.x *= 0.5f; h0.y *= 0.5f; }
                    const float sc = 2.0f * inv_d;
                    float2 p1 = make_float2(R2C*(h1.x - h1.y), R2C*(h1.x + h1.y));
                    float2 q1 = make_float2(R2C*(-h1.x - h1.y), R2C*(h1.x - h1.y));
                    float2 i1 = make_float2(-h1.y, h1.x);
                    float2 i2 = make_float2(-h2.y, h2.x);
                    float2 n2 = make_float2( h2.y, -h2.x);
                    float2 p3 = make_float2(R2C*(h3.x - h3.y), R2C*(h3.x + h3.y));
                    float2 q3 = make_float2(R2C*(-h3.x - h3.y), R2C*(h3.x - h3.y));
                    float2 i3 = make_float2(-h3.y, h3.x);
                    float2 a02 = cadd(h0, h2), s02 = csub(h0, h2);
                    float2 s0 = cadd(a02, cadd(h1, h3));
                    float2 s4 = csub(a02, cadd(h1, h3));
                    float2 s2 = cadd(s02, csub(i1, i3));
                    float2 s6 = csub(s02, csub(i1, i3));
                    float2 b0i = cadd(h0, i2);
                    float2 b0n = cadd(h0, n2);
                    float2 s1 = cadd(b0i, cadd(p1, q3));
                    float2 s5 = csub(b0i, cadd(p1, q3));
                    float2 s3 = cadd(b0n, cadd(q1, p3));
                    float2 s7 = csub(b0n, cadd(q1, p3));
                    float2* Bp = BC + q * (8*BRS) + u2;
                    Bp[0*BRS] = make_float2(s0.x*sc, s0.y*sc);
                    Bp[1*BRS] = make_float2(s1.x*sc, s1.y*sc);
                    Bp[2*BRS] = make_float2(s2.x*sc, s2.y*sc);
                    Bp[3*BRS] = make_float2(s3.x*sc, s3.y*sc);
                    Bp[4*BRS] = make_float2(s4.x*sc, s4.y*sc);
                    Bp[5*BRS] = make_float2(s5.x*sc, s5.y*sc);
                    Bp[6*BRS] = make_float2(s6.x*sc, s6.y*sc);
                    Bp[7*BRS] = make_float2(s7.x*sc, s7.y*sc);
                } else {
                    int u2 = i - 260;
                    Ny[u2] = ((u2 & 1) ? -inv_d : inv_d) * Gs[16*GS + u2].x;
                }
            }
        }
        __syncthreads();
        // ---- acc: v = lane; b128 paired BC reads; register twiddle recurrence
        {
            #pragma unroll
            for (int q = 0; q < 4; ++q) {
                const float4* Bq = (const float4*)(AbBC + q * (8*BRS) + sv * BRS + wv * 16);
                float tx = tq.x, ty = tq.y;
                #pragma unroll
                for (int jp = 0; jp < 8; ++jp) {
                    float4 bb = Bq[jp];
                    acc[2*jp]   = fmaf(bb.x, tx, fmaf(-bb.y, ty, acc[2*jp]));
                    acc[2*jp+1] = fmaf(bb.z, tx, fmaf(-bb.w, ty, acc[2*jp+1]));
                }
                tq = cmul(tq, wvp);
            }
            if (cg == 0) {
                float sgn = (lane & 1) ? -inv_d : inv_d;
                #pragma unroll
                for (int j = 0; j < 16; ++j) acc[j] = fmaf(sgn, Ny[wv * 16 + j], acc[j]);
            }
            if (t < 129) {
                int sr = vr & 7;
                int vpr = (96 + vr) & 127;
                float a = accR;
                #pragma unroll
                for (int q = 0; q < 4; ++q) {
                    float2 tt = tw[((4*cg + q) * vpr) & 127];
                    float2 bv = AbBC[q * (8*BRS) + sr * BRS + ur];
                    a = fmaf(bv.x, tt.x, fmaf(-bv.y, tt.y, a));
                }
                if (cg == 0) a += (vr & 1) ? -inv_d * Ny[ur] : inv_d * Ny[ur];
                accR = a;
            }
        }
        __syncthreads();   // before next chunk's stage1 rewrites Ab/BC
    }

    // ---- top-2 (lax.top_k tie-break: lower flat index wins)
    float v1 = -INFINITY, v2 = -INFINITY;
    int i1 = 0x7fffffff, i2 = 0x7fffffff;
    #pragma unroll
    for (int j = 0; j < 16; ++j) {
        float val = acc[j];
        int uu = wv * 16 + j;
        int fl = (32 + uu) * D + (32 + lane);
        if (better(val, fl, v1, i1)) { v2 = v1; i2 = i1; v1 = val; i1 = fl; }
        else if (better(val, fl, v2, i2)) { v2 = val; i2 = fl; }
    }
    if (t < 129) {
        int fl = (32 + ur) * D + (32 + vr);
        if (better(accR, fl, v1, i1)) { v2 = v1; i2 = i1; v1 = accR; i1 = fl; }
        else if (better(accR, fl, v2, i2)) { v2 = accR; i2 = fl; }
    }
    for (int off = 32; off > 0; off >>= 1) {
        float b1 = __shfl_down(v1, off); int j1 = __shfl_down(i1, off);
        float b2 = __shfl_down(v2, off); int j2 = __shfl_down(i2, off);
        if (better(b1, j1, v1, i1)) {
            float nv2; int ni2;
            if (better(v1, i1, b2, j2)) { nv2 = v1; ni2 = i1; } else { nv2 = b2; ni2 = j2; }
            v1 = b1; i1 = j1; v2 = nv2; i2 = ni2;
        } else {
            if (better(b1, j1, v2, i2)) { v2 = b1; i2 = j1; }
        }
    }
    int wave = tid >> 6;   // 0..7 block-wide; half0 waves 0-3, half1 waves 4-7
    if ((tid & 63) == 0) {
        redv[wave*2]   = v1; redi[wave*2]   = i1;
        redv[wave*2+1] = v2; redi[wave*2+1] = i2;
    }
    __syncthreads();
    if (t == 0) {
        float r1 = -INFINITY, r2 = -INFINITY;
        int q1 = 0x7fffffff, q2 = 0x7fffffff;
        for (int i = 0; i < 8; ++i) {
            float val = redv[half*8 + i]; int fl = redi[half*8 + i];
            if (better(val, fl, r1, q1)) { r2 = r1; q2 = q1; r1 = val; q1 = fl; }
            else if (better(val, fl, r2, q2)) { r2 = val; q2 = fl; }
        }
        int base = (b * NK + k) * 2;
        outv[base]     = r1;
        outv[base + 1] = r2;
        float* os = outv + NB*NK*2;
        os[(base    )*2 + 0] = (float)(q1 / D - 64);
        os[(base    )*2 + 1] = (float)(q1 % D - 64);
        os[(base + 1)*2 + 0] = (float)(q2 / D - 64);
        os[(base + 1)*2 + 1] = (float)(q2 % D - 64);
    }
}

// ---------------- launcher ----------------

extern "C" void kernel_launch(void* const* d_in, const int* in_sizes, int n_in,
                              void* d_out, int out_size, void* d_ws, size_t ws_size,
                              hipStream_t stream) {
    const float* vol   = (const float*)d_in[0];   // (128,128,128)
    const float* parts = (const float*)d_in[1];   // (8,128,128)
    const float* ctf   = (const float*)d_in[2];   // (8,128,65)
    const float* euler = (const float*)d_in[3];   // (125,3)
    float* out = (float*)d_out;

    const int VOLC = D * SLAB;
    float2* bufA   = (float2*)d_ws;                    // vol x-pass out; later final vol_rfft
    float2* bufB   = bufA + VOLC;                      // vol y-pass out
    float2* pT1    = bufB + VOLC;                      // parts x-pass (8*SLAB)
    float2* ST     = pT1 + NB * SLAB;                  // ctf * parts_rfft, transposed [b][x][m]
    float2* PJT    = ST + NB * W * D;                  // projs transposed [k][w][h]
    float*  CT     = (float*)(PJT + NK * W * D);       // ctf transposed [b][x][m]
    float*  rot    = CT + NB * W * D;                  // (125,9)

    // K1: vol x-FFT | parts x-FFT | rot | ctf transpose
    k1_kernel<<<805, 256, 0, stream>>>(vol, parts, ctf, euler, bufA, pT1, CT, rot);
    // K2: vol y-FFT | parts y-FFT (transposed, ctf folded in)
    k2_kernel<<<277, 256, 0, stream>>>(bufA, bufB, pT1, ST, CT);
    // K3: vol z-FFT
    k3_kernel<<<260, 256, 0, stream>>>(bufB, bufA);
    // K4: central-slice projections (transposed write, XCD-swizzled, disc early-out)
    proj_kernel<<<4063, 256, 0, stream>>>(bufA, rot, PJT);
    // K5: fused correlation + windowed top-2 (2 pairs per 512-thread block)
    corr_kernel<<<500, 512, 0, stream>>>(ST, PJT, out);
}

// Round 14
// 74.610 us; speedup vs baseline: 1.0154x; 1.0154x over previous
//
#include <hip/hip_runtime.h>
#include <math.h>

#define D 128
#define W 65            // D/2+1
#define NK 125
#define NB 8
#define SLAB (D*W)      // 8320 elements per slab
#define TWO_PI 6.28318530717958647692f
#define R2C 0.70710678118654752440f
#define C8C 0.92387953251128675613f
#define S8C 0.38268343236508977173f
#define ARS 146         // Ab row stride (float2) per column l
#define GS  67          // Gs row stride (float2): 65 needed outputs + pad
#define BRS 68          // BC row stride (float2), even -> 16B-aligned rows

// ---------------- helpers ----------------

__device__ __forceinline__ bool better(float va, int ia, float vb, int ib) {
    return (va > vb) || (va == vb && ia < ib);
}
__device__ __forceinline__ float2 cmul(float2 a, float2 b) {
    return make_float2(a.x*b.x - a.y*b.y, a.x*b.y + a.y*b.x);
}
__device__ __forceinline__ void cmac(float2& acc, float2 a, float2 b) {
    acc.x = fmaf(a.x, b.x, fmaf(-a.y, b.y, acc.x));
    acc.y = fmaf(a.x, b.y, fmaf( a.y, b.x, acc.y));
}
__device__ __forceinline__ float2 cadd(float2 a, float2 b){ return make_float2(a.x+b.x, a.y+b.y); }
__device__ __forceinline__ float2 csub(float2 a, float2 b){ return make_float2(a.x-b.x, a.y-b.y); }

// forward 8-pt FFT: a[r] = sum_j x[j] e^{-2pi i j r/8}
__device__ __forceinline__ void fft8_fwd(const float2* x, float2* a) {
    float2 e0 = x[0], o0 = x[1], e1 = x[2], o1 = x[3];
    float2 e2 = x[4], o2 = x[5], e3 = x[6], o3 = x[7];
    float2 t0 = cadd(e0, e2), t1 = csub(e0, e2);
    float2 t2 = cadd(e1, e3), t3 = csub(e1, e3);
    float2 E0 = cadd(t0, t2), E2 = csub(t0, t2);
    float2 E1 = make_float2(t1.x + t3.y, t1.y - t3.x);
    float2 E3 = make_float2(t1.x - t3.y, t1.y + t3.x);
    float2 u0 = cadd(o0, o2), u1 = csub(o0, o2);
    float2 u2 = cadd(o1, o3), u3 = csub(o1, o3);
    float2 O0 = cadd(u0, u2), O2 = csub(u0, u2);
    float2 O1 = make_float2(u1.x + u3.y, u1.y - u3.x);
    float2 O3 = make_float2(u1.x - u3.y, u1.y + u3.x);
    float2 w1 = make_float2(R2C*(O1.x + O1.y), R2C*(O1.y - O1.x));
    float2 w2 = make_float2(O2.y, -O2.x);
    float2 w3 = make_float2(R2C*(O3.y - O3.x), -R2C*(O3.x + O3.y));
    a[0] = cadd(E0, O0); a[4] = csub(E0, O0);
    a[1] = cadd(E1, w1); a[5] = csub(E1, w1);
    a[2] = cadd(E2, w2); a[6] = csub(E2, w2);
    a[3] = cadd(E3, w3); a[7] = csub(E3, w3);
}

// inverse 8-pt DFT: a[r] = sum_j x[j] e^{+2pi i j r/8}
__device__ __forceinline__ void ifft8_reg(const float2* x, float2* a) {
    float2 e0 = x[0], o0 = x[1], e1 = x[2], o1 = x[3];
    float2 e2 = x[4], o2 = x[5], e3 = x[6], o3 = x[7];
    float2 t0 = cadd(e0, e2), t1 = csub(e0, e2);
    float2 t2 = cadd(e1, e3), t3 = csub(e1, e3);
    float2 E0 = cadd(t0, t2), E2 = csub(t0, t2);
    float2 E1 = make_float2(t1.x - t3.y, t1.y + t3.x);
    float2 E3 = make_float2(t1.x + t3.y, t1.y - t3.x);
    float2 u0 = cadd(o0, o2), u1 = csub(o0, o2);
    float2 u2 = cadd(o1, o3), u3 = csub(o1, o3);
    float2 O0 = cadd(u0, u2), O2 = csub(u0, u2);
    float2 O1 = make_float2(u1.x - u3.y, u1.y + u3.x);
    float2 O3 = make_float2(u1.x + u3.y, u1.y - u3.x);
    float2 w1o = make_float2(R2C*(O1.x - O1.y), R2C*(O1.x + O1.y));
    float2 w2o = make_float2(-O2.y, O2.x);
    float2 w3o = make_float2(R2C*(-O3.x - O3.y), R2C*(O3.x - O3.y));
    a[0] = cadd(E0, O0); a[4] = csub(E0, O0);
    a[1] = cadd(E1, w1o); a[5] = csub(E1, w1o);
    a[2] = cadd(E2, w2o); a[6] = csub(E2, w2o);
    a[3] = cadd(E3, w3o); a[7] = csub(E3, w3o);
}

// ---------------- batched 128-pt FFT: fft16 regs + radix-8 second stage -----
// MODE 0: real rows (float in, contiguous), write k<=64 to out[l*65+k]
// MODE 1: complex, base=(l/65)*SLAB+l%65, stride 65, shift-folded, same layout
// MODE 2: complex, base=l, stride SLAB, shift-folded, same layout
//         (+disc skip: lines with x^2+(y-64)^2 > 66^2 are never read by proj)
// MODE 4: MODE1 + transposed write + ctf multiply (S = parts_rfft * ctf)

template<int MODE>
__device__ __forceinline__ void fft128v2(const float* __restrict__ inf,
                                         const float2* __restrict__ inc,
                                         float2* __restrict__ out,
                                         const float* __restrict__ ct,
                                         int l0, int nlines,
                                         float2* __restrict__ Fl,
                                         float2* __restrict__ twf) {
    int tid = threadIdx.x;
    int line, t;
    if (MODE == 0) { t = tid & 7; line = tid >> 3; }
    else           { line = tid & 31; t = tid >> 5; }
    int l = l0 + line;
    bool live = (l < nlines);
    if (MODE == 2) {
        int ys = l / 65, xx = l - ys * 65;
        int dy = ys - 64;
        if (xx * xx + dy * dy > 4356) live = false;   // never read by proj
    }

    if (tid < 128) {
        float s, c;
        sincosf(-TWO_PI * (float)tid / 128.0f, &s, &c);
        twf[tid] = make_float2(c, s);
    }

    int base = 0, stride = 1;
    if (MODE == 1 || MODE == 4) { base = (l / W) * SLAB + (l % W); stride = W; }
    else if (MODE == 2) { base = l; stride = SLAB; }

    float2 xe[8], xo[8];
    if (live) {
        if (MODE == 0) {
            const float* r = inf + (size_t)l * D;
            #pragma unroll
            for (int j = 0; j < 8; ++j) {
                xe[j] = make_float2(r[t + 16*j], 0.f);
                xo[j] = make_float2(r[t + 8 + 16*j], 0.f);
            }
        } else {
            #pragma unroll
            for (int j = 0; j < 8; ++j) {
                xe[j] = inc[base + (t + 16*j) * stride];
                xo[j] = inc[base + (t + 8 + 16*j) * stride];
            }
        }
    } else {
        #pragma unroll
        for (int j = 0; j < 8; ++j) { xe[j] = make_float2(0,0); xo[j] = make_float2(0,0); }
    }
    float2 E[8], O[8];
    fft8_fwd(xe, E);
    fft8_fwd(xo, O);
    {
        const float2 w16[8] = {
            { 1.f, 0.f }, { C8C, -S8C }, { R2C, -R2C }, { S8C, -C8C },
            { 0.f, -1.f }, { -S8C, -C8C }, { -R2C, -R2C }, { -C8C, -S8C }
        };
        float2* Fp = Fl + line * 137 + t * 17;
        #pragma unroll
        for (int kk = 0; kk < 8; ++kk) {
            float2 wo = cmul(w16[kk], O[kk]);
            Fp[kk]     = cadd(E[kk], wo);
            Fp[kk + 8] = csub(E[kk], wo);
        }
    }
    __syncthreads();
    if (live) {
        const float2* Fr = Fl + line * 137;
        #pragma unroll
        for (int half = 0; half < 2; ++half) {
            int kk = t + 8 * half;
            float2 Gv[8];
            #pragma unroll
            for (int tt = 0; tt < 8; ++tt) {
                Gv[tt] = cmul(Fr[tt * 17 + kk], twf[(tt * kk) & 127]);
            }
            float2 o[8];
            fft8_fwd(Gv, o);   // o[s] = out frequency k = kk + 16 s
            if (MODE == 0) {
                #pragma unroll
                for (int s = 0; s < 8; ++s) {
                    int kf = kk + 16 * s;
                    if (kf <= 64) out[(size_t)l * W + kf] = o[s];
                }
            } else {
                #pragma unroll
                for (int s = 0; s < 8; ++s) {
                    int slot = (kk + 16 * s) ^ 64;   // fftshift fold
                    if (MODE == 4) {
                        float cf = ct[(size_t)l * D + slot];
                        out[(size_t)l * D + slot] = make_float2(o[s].x * cf, o[s].y * cf);
                    } else {
                        out[base + slot * stride] = o[s];
                    }
                }
            }
        }
    }
}

// ---------------- merged prologue kernels ----------------

// K1: vol x-FFT (512 blks) | parts x-FFT (32) | rot (1) | ctf transpose (260)
__global__ __launch_bounds__(256) void k1_kernel(const float* __restrict__ vol,
                                                 const float* __restrict__ parts,
                                                 const float* __restrict__ ctf,
                                                 const float* __restrict__ euler,
                                                 float2* __restrict__ bufA,
                                                 float2* __restrict__ pT1,
                                                 float* __restrict__ CT,
                                                 float* __restrict__ rot) {
    __shared__ float2 Fl[32 * 137];
    __shared__ float2 twf[128];
    int bid = blockIdx.x;
    int tid = threadIdx.x;
    if (bid < 512) {
        fft128v2<0>(vol, nullptr, bufA, nullptr, bid * 32, D*D, Fl, twf);
    } else if (bid < 544) {
        fft128v2<0>(parts, nullptr, pT1, nullptr, (bid - 512) * 32, NB*D, Fl, twf);
    } else if (bid == 544) {
        int k = tid;
        if (k < NK) {
            const float d2r = 0.017453292519943295f;
            float a = euler[k*3+0]*d2r, b = euler[k*3+1]*d2r, c = euler[k*3+2]*d2r;
            float sa, ca, sb, cb, sc, cc;
            sincosf(a, &sa, &ca); sincosf(b, &sb, &cb); sincosf(c, &sc, &cc);
            rot[k*9+0] =  ca*cb*cc - sa*sc;
            rot[k*9+1] = -ca*cb*sc - sa*cc;
            rot[k*9+2] =  ca*sb;
            rot[k*9+3] =  sa*cb*cc + ca*sc;
            rot[k*9+4] = -sa*cb*sc + ca*cc;
            rot[k*9+5] =  sa*sb;
            rot[k*9+6] = -sb*cc;
            rot[k*9+7] =  sb*sc;
            rot[k*9+8] =  cb;
        }
    } else {
        int i = (bid - 545) * 256 + tid;
        if (i < NB * W * D) {
            int m = i & (D-1);
            int t2 = i >> 7;
            int x = t2 % W;
            int b = t2 / W;
            CT[i] = ctf[b * SLAB + m * W + x];
        }
    }
}

// K2: vol y-FFT (260 blks) | parts y-FFT transposed with ctf fold (17)
__global__ __launch_bounds__(256) void k2_kernel(const float2* __restrict__ bufA,
                                                 float2* __restrict__ bufB,
                                                 const float2* __restrict__ pT1,
                                                 float2* __restrict__ ST,
                                                 const float* __restrict__ CT) {
    __shared__ float2 Fl[32 * 137];
    __shared__ float2 twf[128];
    int bid = blockIdx.x;
    if (bid < 260) fft128v2<1>(nullptr, bufA, bufB, nullptr, bid * 32, D*W, Fl, twf);
    else           fft128v2<4>(nullptr, pT1, ST, CT, (bid - 260) * 32, NB*W, Fl, twf);
}

// K3: vol z-FFT (disc-skipped: ~18% of lines are never read by proj)
__global__ __launch_bounds__(256) void k3_kernel(const float2* __restrict__ bufB,
                                                 float2* __restrict__ bufA) {
    __shared__ float2 Fl[32 * 137];
    __shared__ float2 twf[128];
    fft128v2<2>(nullptr, bufB, bufA, nullptr, blockIdx.x * 32, SLAB, Fl, twf);
}

// ---------------- central-slice projection (transposed write) ----------------
// Bijective XCD-chunked block swizzle + early-out beyond the Nyquist disc.

__global__ __launch_bounds__(256) void proj_kernel(const float2* __restrict__ vol,
                                                   const float* __restrict__ rot,
                                                   float2* __restrict__ projT) {
    int bid = blockIdx.x;
    int xcd = bid & 7, ii = bid >> 3;
    int wg = (xcd < 7) ? (xcd * 508 + ii) : (3556 + ii);
    int idx = wg * 256 + threadIdx.x;
    if (idx >= NK * D * W) return;
    int h = idx & (D-1);
    int t2 = idx >> 7;
    int w = t2 % W;
    int k = t2 / W;
    int yy = h - 64;
    if (w*w + yy*yy > 4096) { projT[idx] = make_float2(0.f, 0.f); return; }
    float x = (float)w;
    float y = (float)yy;
    const float* R = rot + k*9;
    float rx = R[0]*x + R[1]*y;
    float ry = R[3]*x + R[4]*y;
    float rz = R[6]*x + R[7]*y;
    bool neg = rx < 0.0f;
    if (neg) { rx = -rx; ry = -ry; rz = -rz; }
    float xi = rx;
    float yi = ry + 64.0f;
    float zi = rz + 64.0f;
    float z0 = floorf(zi), y0 = floorf(yi), x0 = floorf(xi);
    float tz = zi - z0, ty = yi - y0, tx = xi - x0;
    int z0i = (int)z0, y0i = (int)y0, x0i = (int)x0;
    float ar = 0.f, ai = 0.f;
    for (int dz = 0; dz < 2; ++dz) {
        float wz = dz ? tz : 1.0f - tz;
        int zc = z0i + dz;
        bool vz = (zc >= 0) && (zc < D);
        int zx = min(max(zc, 0), D-1);
        for (int dy = 0; dy < 2; ++dy) {
            float wy = dy ? ty : 1.0f - ty;
            int yc = y0i + dy;
            bool vy = (yc >= 0) && (yc < D);
            int yx = min(max(yc, 0), D-1);
            for (int dx = 0; dx < 2; ++dx) {
                float wx = dx ? tx : 1.0f - tx;
                int xc = x0i + dx;
                bool vx = (xc >= 0) && (xc < W);
                int xx = min(max(xc, 0), W-1);
                float wt = (vz && vy && vx) ? wz*wy*wx : 0.0f;
                float2 v = vol[zx * SLAB + yx * W + xx];
                ar = fmaf(wt, v.x, ar);
                ai = fmaf(wt, v.y, ai);
            }
        }
    }
    if (neg) ai = -ai;
    projT[idx] = make_float2(ar, ai);
}

// ---------------- fused correlate + windowed irfft2 + top2 ----------------
// One block per (b,k), XCD-chunked swizzle. 4 chunks x 16 columns (+Nyquist in
// chunk 0). Round-12 best config: block-wide phases, Gs-shrink, b128 acc reads,
// launch_bounds(256,3) (84-VGPR cap, 3 blocks/CU). Spill watchdog: WRITE_SIZE
// must stay ~26 KB.

__global__ __launch_bounds__(256, 3) void corr_kernel(const float2* __restrict__ ST,
                                                      const float2* __restrict__ PJT,
                                                      float* __restrict__ outv) {
    __shared__ float2 tw[128];                    // e^{+2 pi i n/128}
    __shared__ __align__(16) float2 AbBC[17*ARS]; // stage1 out [l][r][m0]; BC overlays
    __shared__ float2 Gs[17*GS];                  // needed column-iFFT outputs [l][u2]
    __shared__ float  Ny[65];
    __shared__ float  redv[8];
    __shared__ int    redi[8];

    int g = blockIdx.x;
    int logical = (g & 7) * 125 + (g >> 3);   // XCD-chunked: bijective for 1000
    int k = logical >> 3;
    int b = logical & 7;
    int tid = threadIdx.x;
    const float inv_d = 1.0f / 128.0f;

    if (tid < 128) {
        float s, c;
        sincosf(TWO_PI * (float)tid / 128.0f, &s, &c);
        tw[tid] = make_float2(c, s);
    }

    const float2* Sb = ST + b * (W * D);
    const float2* Jk = PJT + k * (W * D);

    int lane = tid & 63;        // acc: v = lane
    int wv = tid >> 6;          // acc uu block = wv*16 + j
    int sv = lane & 7;
    int vp = (96 + lane) & 127;
    float acc[16];
    #pragma unroll
    for (int j = 0; j < 16; ++j) acc[j] = 0.0f;
    float accR = 0.0f;          // rim accumulator (tid<129)
    int ur = 0, vr = 0;
    if (tid < 129) { if (tid < 65) { ur = 64; vr = tid; } else { ur = tid - 65; vr = 64; } }

    __syncthreads();

    float2 wvp = tw[vp];
    float2 tq = make_float2(1.0f, 0.0f);   // tw[x*vp], x running 0..15

    for (int cg = 0; cg < 4; ++cg) {
        // ---- stage1: product + 8-pt iFFT over m1 + pre-twiddle -> Ab
        {
            int lim1 = (cg == 0) ? 17 * 16 : 16 * 16;
            for (int i = tid; i < lim1; i += 256) {
                int l = i >> 4, m0 = i & 15;
                int x = (l < 16) ? (4*cg + (l >> 2) + 16 * (l & 3)) : 64;
                const float2* Sx = Sb + x * 128 + m0;
                const float2* Jx = Jk + x * 128 + m0;
                float2 p[8];
                #pragma unroll
                for (int j = 0; j < 8; ++j) {
                    float2 s = Sx[16*j];
                    float2 pj = Jx[16*j];
                    p[j] = make_float2(s.x*pj.x + s.y*pj.y, s.y*pj.x - s.x*pj.y);
                }
                float2 A[8];
                ifft8_reg(p, A);
                float2* dst = AbBC + l * ARS + m0;
                dst[0] = A[0];
                #pragma unroll
                for (int r = 1; r < 8; ++r) dst[r*18] = cmul(A[r], tw[(r * m0) & 127]);
            }
        }
        __syncthreads();
        // ---- stage2: 16-pt register iFFT per (l, r); store only needed k's
        {
            int lim2 = (cg == 0) ? 136 : 128;
            for (int i = tid; i < lim2; i += 256) {
                int l, r;
                if (i < 128) { l = i & 15; r = i >> 4; }
                else         { l = 16; r = i - 128; }
                const float4* Ar = (const float4*)(AbBC + l * ARS + r * 18);
                float2 xe[8], xo[8];
                #pragma unroll
                for (int j = 0; j < 8; ++j) {
                    float4 a = Ar[j];
                    xe[j] = make_float2(a.x, a.y);
                    xo[j] = make_float2(a.z, a.w);
                }
                float2 E[8], O[8];
                ifft8_reg(xe, E);
                ifft8_reg(xo, O);
                const float2 w16p[8] = {
                    { 1.f, 0.f }, { C8C, S8C }, { R2C, R2C }, { S8C, C8C },
                    { 0.f, 1.f }, { -S8C, C8C }, { -R2C, R2C }, { -C8C, S8C }
                };
                float2* Gl = Gs + l * GS;
                #pragma unroll
                for (int t = 0; t < 8; ++t) {
                    float2 wo = cmul(w16p[t], O[t]);
                    float2 lowv  = cadd(E[t], wo);   // freq k = r + 8t
                    float2 highv = csub(E[t], wo);   // freq k + 64
                    int klow = r + 8*t;
                    if (t <= 3) Gl[klow + 32] = lowv;            // k<=31 -> u2=k+32
                    if (t == 4 && r == 0) Gl[64] = lowv;         // k=32  -> u2=64
                    if (t >= 4) Gl[klow - 32] = highv;           // k+64>=96 -> u2=k-32
                }
            }
        }
        __syncthreads();
        // ---- B stage: read Gs directly by u2, scale, x1 butterfly -> BC, Ny
        {
            float2* BC = AbBC;   // Ab dead; overlay
            int lim = (cg == 0) ? 325 : 260;
            for (int i = tid; i < lim; i += 256) {
                if (i < 260) {
                    int q = i / 65;
                    int u2 = i - q * 65;
                    float sg = (u2 & 1) ? -inv_d : inv_d;
                    const float2* Gq = Gs + (4*q) * GS + u2;
                    float2 h0 = Gq[0*GS];
                    float2 h1 = Gq[1*GS];
                    float2 h2 = Gq[2*GS];
                    float2 h3 = Gq[3*GS];
                    h0.x *= sg; h0.y *= sg; h1.x *= sg; h1.y *= sg;
                    h2.x *= sg; h2.y *= sg; h3.x *= sg; h3.y *= sg;
                    if (cg == 0 && q == 0) { h0.x *= 0.5f; h0.y *= 0.5f; }
                    const float sc = 2.0f * inv_d;
                    float2 p1 = make_float2(R2C*(h1.x - h1.y), R2C*(h1.x + h1.y));
                    float2 q1 = make_float2(R2C*(-h1.x - h1.y), R2C*(h1.x - h1.y));
                    float2 i1 = make_float2(-h1.y, h1.x);
                    float2 i2 = make_float2(-h2.y, h2.x);
                    float2 n2 = make_float2( h2.y, -h2.x);
                    float2 p3 = make_float2(R2C*(h3.x - h3.y), R2C*(h3.x + h3.y));
                    float2 q3 = make_float2(R2C*(-h3.x - h3.y), R2C*(h3.x - h3.y));
                    float2 i3 = make_float2(-h3.y, h3.x);
                    float2 a02 = cadd(h0, h2), s02 = csub(h0, h2);
                    float2 s0 = cadd(a02, cadd(h1, h3));
                    float2 s4 = csub(a02, cadd(h1, h3));
                    float2 s2 = cadd(s02, csub(i1, i3));
                    float2 s6 = csub(s02, csub(i1, i3));
                    float2 b0i = cadd(h0, i2);
                    float2 b0n = cadd(h0, n2);
                    float2 s1 = cadd(b0i, cadd(p1, q3));
                    float2 s5 = csub(b0i, cadd(p1, q3));
                    float2 s3 = cadd(b0n, cadd(q1, p3));
                    float2 s7 = csub(b0n, cadd(q1, p3));
                    float2* Bp = BC + q * (8*BRS) + u2;
                    Bp[0*BRS] = make_float2(s0.x*sc, s0.y*sc);
                    Bp[1*BRS] = make_float2(s1.x*sc, s1.y*sc);
                    Bp[2*BRS] = make_float2(s2.x*sc, s2.y*sc);
                    Bp[3*BRS] = make_float2(s3.x*sc, s3.y*sc);
                    Bp[4*BRS] = make_float2(s4.x*sc, s4.y*sc);
                    Bp[5*BRS] = make_float2(s5.x*sc, s5.y*sc);
                    Bp[6*BRS] = make_float2(s6.x*sc, s6.y*sc);
                    Bp[7*BRS] = make_float2(s7.x*sc, s7.y*sc);
                } else {
                    int u2 = i - 260;
                    Ny[u2] = ((u2 & 1) ? -inv_d : inv_d) * Gs[16*GS + u2].x;
                }
            }
        }
        __syncthreads();
        // ---- acc: v = lane; b128 paired BC reads; register twiddle recurrence
        {
            #pragma unroll
            for (int q = 0; q < 4; ++q) {
                const float4* Bq = (const float4*)(AbBC + q * (8*BRS) + sv * BRS + wv * 16);
                float tx = tq.x, ty = tq.y;
                #pragma unroll
                for (int jp = 0; jp < 8; ++jp) {
                    float4 bb = Bq[jp];
                    acc[2*jp]   = fmaf(bb.x, tx, fmaf(-bb.y, ty, acc[2*jp]));
                    acc[2*jp+1] = fmaf(bb.z, tx, fmaf(-bb.w, ty, acc[2*jp+1]));
                }
                tq = cmul(tq, wvp);
            }
            if (cg == 0) {
                float sgn = (lane & 1) ? -inv_d : inv_d;
                #pragma unroll
                for (int j = 0; j < 16; ++j) acc[j] = fmaf(sgn, Ny[wv * 16 + j], acc[j]);
            }
            if (tid < 129) {
                int sr = vr & 7;
                int vpr = (96 + vr) & 127;
                float a = accR;
                #pragma unroll
                for (int q = 0; q < 4; ++q) {
                    float2 t = tw[((4*cg + q) * vpr) & 127];
                    float2 bv = AbBC[q * (8*BRS) + sr * BRS + ur];
                    a = fmaf(bv.x, t.x, fmaf(-bv.y, t.y, a));
                }
                if (cg == 0) a += (vr & 1) ? -inv_d * Ny[ur] : inv_d * Ny[ur];
                accR = a;
            }
        }
        __syncthreads();   // before next chunk's stage1 rewrites Ab/BC
    }

    // ---- top-2 (lax.top_k tie-break: lower flat index wins)
    float v1 = -INFINITY, v2 = -INFINITY;
    int i1 = 0x7fffffff, i2 = 0x7fffffff;
    #pragma unroll
    for (int j = 0; j < 16; ++j) {
        float val = acc[j];
        int uu = wv * 16 + j;
        int fl = (32 + uu) * D + (32 + lane);
        if (better(val, fl, v1, i1)) { v2 = v1; i2 = i1; v1 = val; i1 = fl; }
        else if (better(val, fl, v2, i2)) { v2 = val; i2 = fl; }
    }
    if (tid < 129) {
        int fl = (32 + ur) * D + (32 + vr);
        if (better(accR, fl, v1, i1)) { v2 = v1; i2 = i1; v1 = accR; i1 = fl; }
        else if (better(accR, fl, v2, i2)) { v2 = accR; i2 = fl; }
    }
    for (int off = 32; off > 0; off >>= 1) {
        float b1 = __shfl_down(v1, off); int j1 = __shfl_down(i1, off);
        float b2 = __shfl_down(v2, off); int j2 = __shfl_down(i2, off);
        if (better(b1, j1, v1, i1)) {
            float nv2; int ni2;
            if (better(v1, i1, b2, j2)) { nv2 = v1; ni2 = i1; } else { nv2 = b2; ni2 = j2; }
            v1 = b1; i1 = j1; v2 = nv2; i2 = ni2;
        } else {
            if (better(b1, j1, v2, i2)) { v2 = b1; i2 = j1; }
        }
    }
    int wave = tid >> 6;
    if ((tid & 63) == 0) {
        redv[wave*2]   = v1; redi[wave*2]   = i1;
        redv[wave*2+1] = v2; redi[wave*2+1] = i2;
    }
    __syncthreads();
    if (tid == 0) {
        float r1 = -INFINITY, r2 = -INFINITY;
        int q1 = 0x7fffffff, q2 = 0x7fffffff;
        for (int i = 0; i < 8; ++i) {
            float val = redv[i]; int fl = redi[i];
            if (better(val, fl, r1, q1)) { r2 = r1; q2 = q1; r1 = val; q1 = fl; }
            else if (better(val, fl, r2, q2)) { r2 = val; q2 = fl; }
        }
        int base = (b * NK + k) * 2;
        outv[base]     = r1;
        outv[base + 1] = r2;
        float* os = outv + NB*NK*2;
        os[(base    )*2 + 0] = (float)(q1 / D - 64);
        os[(base    )*2 + 1] = (float)(q1 % D - 64);
        os[(base + 1)*2 + 0] = (float)(q2 / D - 64);
        os[(base + 1)*2 + 1] = (float)(q2 % D - 64);
    }
}

// ---------------- launcher ----------------

extern "C" void kernel_launch(void* const* d_in, const int* in_sizes, int n_in,
                              void* d_out, int out_size, void* d_ws, size_t ws_size,
                              hipStream_t stream) {
    const float* vol   = (const float*)d_in[0];   // (128,128,128)
    const float* parts = (const float*)d_in[1];   // (8,128,128)
    const float* ctf   = (const float*)d_in[2];   // (8,128,65)
    const float* euler = (const float*)d_in[3];   // (125,3)
    float* out = (float*)d_out;

    const int VOLC = D * SLAB;
    float2* bufA   = (float2*)d_ws;                    // vol x-pass out; later final vol_rfft
    float2* bufB   = bufA + VOLC;                      // vol y-pass out
    float2* pT1    = bufB + VOLC;                      // parts x-pass (8*SLAB)
    float2* ST     = pT1 + NB * SLAB;                  // ctf * parts_rfft, transposed [b][x][m]
    float2* PJT    = ST + NB * W * D;                  // projs transposed [k][w][h]
    float*  CT     = (float*)(PJT + NK * W * D);       // ctf transposed [b][x][m]
    float*  rot    = CT + NB * W * D;                  // (125,9)

    // K1: vol x-FFT | parts x-FFT | rot | ctf transpose
    k1_kernel<<<805, 256, 0, stream>>>(vol, parts, ctf, euler, bufA, pT1, CT, rot);
    // K2: vol y-FFT | parts y-FFT (transposed, ctf folded in)
    k2_kernel<<<277, 256, 0, stream>>>(bufA, bufB, pT1, ST, CT);
    // K3: vol z-FFT (disc-skipped)
    k3_kernel<<<260, 256, 0, stream>>>(bufB, bufA);
    // K4: central-slice projections (transposed write, XCD-swizzled, disc early-out)
    proj_kernel<<<4063, 256, 0, stream>>>(bufA, rot, PJT);
    // K5: fused correlation + windowed top-2
    corr_kernel<<<NB * NK, 256, 0, stream>>>(ST, PJT, out);
}